// Round 1
// baseline (3413.461 us; speedup 1.0000x reference)
//
#include <hip/hip_runtime.h>

#define HD 1024
#define BT 2048
#define NEXP 6
#define MAXR 4096

// ---------------- Threefry-2x32 (matches JAX) ----------------
__host__ __device__ static inline unsigned rotl32(unsigned v, int n) {
  return (v << n) | (v >> (32 - n));
}

__host__ __device__ static inline void tf2x32(unsigned k0, unsigned k1,
                                              unsigned x0, unsigned x1,
                                              unsigned* o0, unsigned* o1) {
  unsigned ks0 = k0, ks1 = k1, ks2 = k0 ^ k1 ^ 0x1BD11BDAu;
  x0 += ks0; x1 += ks1;
  const int ra[4] = {13, 15, 26, 6};
  const int rb[4] = {17, 29, 16, 24};
  #pragma unroll
  for (int r = 0; r < 4; ++r) { x0 += x1; x1 = rotl32(x1, ra[r]); x1 ^= x0; }
  x0 += ks1; x1 += ks2 + 1u;
  #pragma unroll
  for (int r = 0; r < 4; ++r) { x0 += x1; x1 = rotl32(x1, rb[r]); x1 ^= x0; }
  x0 += ks2; x1 += ks0 + 2u;
  #pragma unroll
  for (int r = 0; r < 4; ++r) { x0 += x1; x1 = rotl32(x1, ra[r]); x1 ^= x0; }
  x0 += ks0; x1 += ks1 + 3u;
  #pragma unroll
  for (int r = 0; r < 4; ++r) { x0 += x1; x1 = rotl32(x1, rb[r]); x1 ^= x0; }
  x0 += ks1; x1 += ks2 + 4u;
  #pragma unroll
  for (int r = 0; r < 4; ++r) { x0 += x1; x1 = rotl32(x1, ra[r]); x1 ^= x0; }
  x0 += ks2; x1 += ks0 + 5u;
  *o0 = x0; *o1 = x1;
}

// ---------------- init ----------------
__global__ void init_ws_k(int* cnt, float* loss) {
  int t = threadIdx.x;
  if (t < 32) cnt[t] = 0;
  if (t == 32) loss[0] = 0.0f;
}

// ---------------- f32 tiled GEMM: C = A(MxK) @ B(KxN) + bias ----------------
// 128x128 tile, BK=16, 256 threads, 8x8 per thread.
__global__ __launch_bounds__(256) void gemm_bias_k(
    const float* __restrict__ A, const float* __restrict__ Bm,
    const float* __restrict__ bias, float* __restrict__ C,
    int M, int N, int K) {
  __shared__ float As[16][132];
  __shared__ float Bs[16][132];
  int tid = threadIdx.x;
  int tx = tid & 15, ty = tid >> 4;
  int row0 = blockIdx.y * 128, col0 = blockIdx.x * 128;
  float acc[8][8] = {};
  int ar = tid >> 2;            // 0..63
  int ac = (tid & 3) * 4;       // 0,4,8,12
  int br = tid >> 5;            // 0..7
  int bc = (tid & 31) * 4;      // 0..124
  for (int k0 = 0; k0 < K; k0 += 16) {
    #pragma unroll
    for (int i = 0; i < 2; ++i) {
      int r = ar + i * 64;
      float4 v = *(const float4*)&A[(size_t)(row0 + r) * K + k0 + ac];
      As[ac + 0][r] = v.x; As[ac + 1][r] = v.y;
      As[ac + 2][r] = v.z; As[ac + 3][r] = v.w;
    }
    #pragma unroll
    for (int i = 0; i < 2; ++i) {
      int k = br + i * 8;
      float4 v = *(const float4*)&Bm[(size_t)(k0 + k) * N + col0 + bc];
      *(float4*)&Bs[k][bc] = v;
    }
    __syncthreads();
    #pragma unroll
    for (int k = 0; k < 16; ++k) {
      float a[8], b[8];
      #pragma unroll
      for (int i = 0; i < 4; ++i) { a[i] = As[k][ty * 4 + i]; a[4 + i] = As[k][64 + ty * 4 + i]; }
      #pragma unroll
      for (int j = 0; j < 4; ++j) { b[j] = Bs[k][tx * 4 + j]; b[4 + j] = Bs[k][64 + tx * 4 + j]; }
      #pragma unroll
      for (int i = 0; i < 8; ++i)
        #pragma unroll
        for (int j = 0; j < 8; ++j)
          acc[i][j] += a[i] * b[j];
    }
    __syncthreads();
  }
  float4 bias0 = *(const float4*)&bias[col0 + tx * 4];
  float4 bias1 = *(const float4*)&bias[col0 + 64 + tx * 4];
  #pragma unroll
  for (int i = 0; i < 8; ++i) {
    int rr = (i < 4) ? (ty * 4 + i) : (64 + ty * 4 + (i - 4));
    size_t rowoff = (size_t)(row0 + rr) * N;
    float4 v0 = { acc[i][0] + bias0.x, acc[i][1] + bias0.y, acc[i][2] + bias0.z, acc[i][3] + bias0.w };
    *(float4*)&C[rowoff + col0 + tx * 4] = v0;
    float4 v1 = { acc[i][4] + bias1.x, acc[i][5] + bias1.y, acc[i][6] + bias1.z, acc[i][7] + bias1.w };
    *(float4*)&C[rowoff + col0 + 64 + tx * 4] = v1;
  }
}

// ---------------- gating: per-token top2 + threefry keep + lists ----------------
__global__ __launch_bounds__(64) void gating_k(
    const float* __restrict__ xl, const float* __restrict__ wg,
    int* __restrict__ cnt, int* __restrict__ toklist,
    float* __restrict__ g1o, float* __restrict__ g2o,
    float* __restrict__ loss, unsigned key0, unsigned key1) {
  int b = blockIdx.x;
  int lane = threadIdx.x;
  const float* row = xl + (size_t)b * HD;
  float p[NEXP] = {0, 0, 0, 0, 0, 0};
  for (int d = lane; d < HD; d += 64) {
    float xv = row[d];
    const float* w = wg + (size_t)d * NEXP;
    #pragma unroll
    for (int e = 0; e < NEXP; ++e) p[e] += xv * w[e];
  }
  #pragma unroll
  for (int off = 32; off > 0; off >>= 1)
    #pragma unroll
    for (int e = 0; e < NEXP; ++e) p[e] += __shfl_down(p[e], off);
  if (lane == 0) {
    float mx = p[0];
    #pragma unroll
    for (int e = 1; e < NEXP; ++e) mx = fmaxf(mx, p[e]);
    float ex[NEXP], s = 0.0f;
    #pragma unroll
    for (int e = 0; e < NEXP; ++e) { ex[e] = expf(p[e] - mx); s += ex[e]; }
    float raw[NEXP];
    #pragma unroll
    for (int e = 0; e < NEXP; ++e) raw[e] = ex[e] / s;
    int i1 = 0; float gg1 = raw[0];
    #pragma unroll
    for (int e = 1; e < NEXP; ++e) if (raw[e] > gg1) { gg1 = raw[e]; i1 = e; }
    int i2 = -1; float gg2 = -1.0f;
    #pragma unroll
    for (int e = 0; e < NEXP; ++e) {
      float v = (e == i1) ? 0.0f : raw[e];
      if (v > gg2) { gg2 = v; i2 = e; }
    }
    float den = gg1 + gg2 + 1e-9f;
    float g1n = gg1 / den;
    float g2n = gg2 / den;
    // threefry_partitionable uniform bits: counts = (0, b), bits = o0 ^ o1
    unsigned o0, o1;
    tf2x32(key0, key1, 0u, (unsigned)b, &o0, &o1);
    unsigned bits = o0 ^ o1;
    float prob = __uint_as_float((bits >> 9) | 0x3f800000u) - 1.0f;
    int keep = prob < (g2n / 0.2f);
    int s1 = atomicAdd(&cnt[i1], 1);
    toklist[i1 * MAXR + s1] = b;            // dest row b -> expert-1 output slot
    g1o[b] = g1n;
    if (keep) {
      int s2 = atomicAdd(&cnt[i2], 1);
      toklist[i2 * MAXR + s2] = BT + b;     // dest row 2048+b -> expert-2 output slot
      g2o[b] = g2n;
    } else {
      g2o[b] = 0.0f;
    }
    atomicAdd(loss, gg1);                   // sum of unnormalized top-1 prob
  }
}

// ---------------- expert GEMM: eo[dest] = relu(x[tok] @ w1[e]) ----------------
__global__ __launch_bounds__(256) void expert_gemm_k(
    const float* __restrict__ X, const float* __restrict__ W1,
    const int* __restrict__ cnt, const int* __restrict__ toklist,
    float* __restrict__ eo) {
  int e = blockIdx.z;
  int n = cnt[e];
  int row0 = blockIdx.y * 128;
  if (row0 >= n) return;
  const float* Bm = W1 + (size_t)e * HD * HD;
  const int* list = toklist + e * MAXR;
  __shared__ float As[16][132];
  __shared__ float Bs[16][132];
  int tid = threadIdx.x;
  int tx = tid & 15, ty = tid >> 4;
  int col0 = blockIdx.x * 128;
  float acc[8][8] = {};
  int ar = tid >> 2;
  int ac = (tid & 3) * 4;
  int br = tid >> 5;
  int bc = (tid & 31) * 4;
  int tok0 = (row0 + ar < n) ? (list[row0 + ar] & (BT - 1)) : 0;
  int tok1 = (row0 + ar + 64 < n) ? (list[row0 + ar + 64] & (BT - 1)) : 0;
  for (int k0 = 0; k0 < HD; k0 += 16) {
    {
      float4 v0 = *(const float4*)&X[(size_t)tok0 * HD + k0 + ac];
      As[ac + 0][ar] = v0.x; As[ac + 1][ar] = v0.y;
      As[ac + 2][ar] = v0.z; As[ac + 3][ar] = v0.w;
      float4 v1 = *(const float4*)&X[(size_t)tok1 * HD + k0 + ac];
      As[ac + 0][ar + 64] = v1.x; As[ac + 1][ar + 64] = v1.y;
      As[ac + 2][ar + 64] = v1.z; As[ac + 3][ar + 64] = v1.w;
    }
    #pragma unroll
    for (int i = 0; i < 2; ++i) {
      int k = br + i * 8;
      float4 v = *(const float4*)&Bm[(size_t)(k0 + k) * HD + col0 + bc];
      *(float4*)&Bs[k][bc] = v;
    }
    __syncthreads();
    #pragma unroll
    for (int k = 0; k < 16; ++k) {
      float a[8], b[8];
      #pragma unroll
      for (int i = 0; i < 4; ++i) { a[i] = As[k][ty * 4 + i]; a[4 + i] = As[k][64 + ty * 4 + i]; }
      #pragma unroll
      for (int j = 0; j < 4; ++j) { b[j] = Bs[k][tx * 4 + j]; b[4 + j] = Bs[k][64 + tx * 4 + j]; }
      #pragma unroll
      for (int i = 0; i < 8; ++i)
        #pragma unroll
        for (int j = 0; j < 8; ++j)
          acc[i][j] += a[i] * b[j];
    }
    __syncthreads();
  }
  int c0 = col0 + tx * 4, c1 = col0 + 64 + tx * 4;
  #pragma unroll
  for (int i = 0; i < 8; ++i) {
    int rr = (i < 4) ? (ty * 4 + i) : (64 + ty * 4 + (i - 4));
    int r = row0 + rr;
    if (r < n) {
      int dest = list[r];
      float4 v0 = { fmaxf(acc[i][0], 0.0f), fmaxf(acc[i][1], 0.0f),
                    fmaxf(acc[i][2], 0.0f), fmaxf(acc[i][3], 0.0f) };
      *(float4*)&eo[(size_t)dest * HD + c0] = v0;
      float4 v1 = { fmaxf(acc[i][4], 0.0f), fmaxf(acc[i][5], 0.0f),
                    fmaxf(acc[i][6], 0.0f), fmaxf(acc[i][7], 0.0f) };
      *(float4*)&eo[(size_t)dest * HD + c1] = v1;
    }
  }
}

// ---------------- combine (residual + gated expert outputs) + column sums ----------------
__global__ __launch_bounds__(256) void combine_sum_k(
    const float* __restrict__ xl, const float* __restrict__ eo,
    const float* __restrict__ g1o, const float* __restrict__ g2o,
    float* __restrict__ y, float* __restrict__ psum) {
  int c = blockIdx.x * 256 + threadIdx.x;
  int r0 = blockIdx.y * 128;
  float s = 0.0f;
  for (int r = r0; r < r0 + 128; ++r) {
    float v = xl[(size_t)r * HD + c];
    float w1g = g1o[r];
    v += w1g * eo[(size_t)r * HD + c];
    float w2g = g2o[r];
    if (w2g != 0.0f) v += w2g * eo[(size_t)(r + BT) * HD + c];
    y[(size_t)r * HD + c] = v;
    s += v;
  }
  psum[blockIdx.y * HD + c] = s;
}

// ---------------- column sums (for non-MoE BN layers) ----------------
__global__ __launch_bounds__(256) void sum_partial_k(
    const float* __restrict__ src, float* __restrict__ psum) {
  int c = blockIdx.x * 256 + threadIdx.x;
  int r0 = blockIdx.y * 128;
  float s = 0.0f;
  for (int r = r0; r < r0 + 128; ++r) s += src[(size_t)r * HD + c];
  psum[blockIdx.y * HD + c] = s;
}

// ---------------- centered variance partials (two-pass, matches ref) ----------------
__global__ __launch_bounds__(256) void var_partial_k(
    const float* __restrict__ src, const float* __restrict__ psum,
    float* __restrict__ psumsq) {
  int c = blockIdx.x * 256 + threadIdx.x;
  float s = 0.0f;
  #pragma unroll
  for (int i = 0; i < 16; ++i) s += psum[i * HD + c];
  float mu = s * (1.0f / 2048.0f);
  int r0 = blockIdx.y * 128;
  float ss = 0.0f;
  for (int r = r0; r < r0 + 128; ++r) {
    float d = src[(size_t)r * HD + c] - mu;
    ss += d * d;
  }
  psumsq[blockIdx.y * HD + c] = ss;
}

// ---------------- BN apply + relu ----------------
__global__ __launch_bounds__(256) void bn_apply_k(
    const float* __restrict__ src, const float* __restrict__ psum,
    const float* __restrict__ psumsq, const float* __restrict__ gamma,
    const float* __restrict__ beta, float* __restrict__ dst) {
  int c = blockIdx.x * 256 + threadIdx.x;
  float s = 0.0f, ss = 0.0f;
  #pragma unroll
  for (int i = 0; i < 16; ++i) { s += psum[i * HD + c]; ss += psumsq[i * HD + c]; }
  float mu = s * (1.0f / 2048.0f);
  float var = ss * (1.0f / 2048.0f);
  float inv = 1.0f / sqrtf(var + 1e-5f);
  float ga = gamma[c], be = beta[c];
  int r0 = blockIdx.y * 128;
  for (int r = r0; r < r0 + 128; ++r) {
    float v = src[(size_t)r * HD + c];
    float o = ga * (v - mu) * inv + be;
    dst[(size_t)r * HD + c] = fmaxf(o, 0.0f);
  }
}

// ---------------- loss finalize ----------------
__global__ void finalize_loss_k(const float* __restrict__ loss, float* __restrict__ out) {
  if (threadIdx.x == 0) out[BT * 256] = loss[0] * (0.01f * 36.0f / 12288.0f);
}

extern "C" void kernel_launch(void* const* d_in, const int* in_sizes, int n_in,
                              void* d_out, int out_size, void* d_ws, size_t ws_size,
                              hipStream_t stream) {
  const float* x     = (const float*)d_in[0];
  const float* in_W  = (const float*)d_in[1];
  const float* in_b  = (const float*)d_in[2];
  const float* in_g  = (const float*)d_in[3];
  const float* in_be = (const float*)d_in[4];
  const float* sp_W  = (const float*)d_in[5];
  const float* sp_b  = (const float*)d_in[6];
  const float* sp_g  = (const float*)d_in[7];
  const float* sp_be = (const float*)d_in[8];
  const float* sp_gate = (const float*)d_in[9];
  const float* sp_w1 = (const float*)d_in[10];
  const float* dn_W  = (const float*)d_in[11];
  const float* dn_b  = (const float*)d_in[12];
  const float* dn_g  = (const float*)d_in[13];
  const float* dn_be = (const float*)d_in[14];
  const float* out_W = (const float*)d_in[15];
  const float* out_b = (const float*)d_in[16];
  float* out = (float*)d_out;

  float* ws = (float*)d_ws;
  const size_t NEL = (size_t)BT * HD;      // 2M
  float* xl   = ws;
  float* y    = ws + NEL;
  float* h    = ws + 2 * NEL;
  float* eo   = ws + 3 * NEL;              // 4096 x 1024
  float* psum   = ws + 3 * NEL + 2 * NEL;  // after eo (eo = 2*NEL)
  float* psumsq = psum + 16 * HD;
  float* g1o  = psumsq + 16 * HD;
  float* g2o  = g1o + BT;
  float* loss = g2o + BT;
  int* cnt    = (int*)(loss + 16);
  int* toklist = cnt + 32;

  // host-side layer keys: fold_in(key(42), i)
  unsigned lk0[4], lk1[4];
  for (int i = 0; i < 4; ++i) tf2x32(0u, 42u, 0u, (unsigned)i, &lk0[i], &lk1[i]);

  dim3 blk(256);
  init_ws_k<<<1, 64, 0, stream>>>(cnt, loss);

  // input layer: xl = x @ in_W + in_b ; h = relu(bn(xl))
  gemm_bias_k<<<dim3(8, 16), blk, 0, stream>>>(x, in_W, in_b, xl, BT, HD, 2048);
  sum_partial_k<<<dim3(4, 16), blk, 0, stream>>>(xl, psum);
  var_partial_k<<<dim3(4, 16), blk, 0, stream>>>(xl, psum, psumsq);
  bn_apply_k<<<dim3(4, 16), blk, 0, stream>>>(xl, psum, psumsq, in_g, in_be, h);

  // sparse MoE layers
  for (int i = 0; i < 4; ++i) {
    gemm_bias_k<<<dim3(8, 16), blk, 0, stream>>>(h, sp_W + (size_t)i * HD * HD,
                                                 sp_b + i * HD, xl, BT, HD, HD);
    gating_k<<<BT, 64, 0, stream>>>(xl, sp_gate + (size_t)i * HD * NEXP,
                                    cnt + i * 8, toklist, g1o, g2o, loss,
                                    lk0[i], lk1[i]);
    expert_gemm_k<<<dim3(8, 32, NEXP), blk, 0, stream>>>(
        xl, sp_w1 + (size_t)i * NEXP * HD * HD, cnt + i * 8, toklist, eo);
    combine_sum_k<<<dim3(4, 16), blk, 0, stream>>>(xl, eo, g1o, g2o, y, psum);
    var_partial_k<<<dim3(4, 16), blk, 0, stream>>>(y, psum, psumsq);
    bn_apply_k<<<dim3(4, 16), blk, 0, stream>>>(y, psum, psumsq, sp_g + i * HD,
                                                sp_be + i * HD, h);
  }

  // dense layers
  for (int i = 0; i < 4; ++i) {
    gemm_bias_k<<<dim3(8, 16), blk, 0, stream>>>(h, dn_W + (size_t)i * HD * HD,
                                                 dn_b + i * HD, xl, BT, HD, HD);
    sum_partial_k<<<dim3(4, 16), blk, 0, stream>>>(xl, psum);
    var_partial_k<<<dim3(4, 16), blk, 0, stream>>>(xl, psum, psumsq);
    bn_apply_k<<<dim3(4, 16), blk, 0, stream>>>(xl, psum, psumsq, dn_g + i * HD,
                                                dn_be + i * HD, h);
  }

  // output projection: out = h @ out_W + out_b
  gemm_bias_k<<<dim3(2, 16), blk, 0, stream>>>(h, out_W, out_b, out, BT, 256, HD);
  finalize_loss_k<<<1, 64, 0, stream>>>(loss, out);
}

// Round 2
// 2244.048 us; speedup vs baseline: 1.5211x; 1.5211x over previous
//
#include <hip/hip_runtime.h>

#define HD 1024
#define BT 2048
#define NEXP 6
#define MAXR 4096

// ---------------- Threefry-2x32 (matches JAX) ----------------
__host__ __device__ static inline unsigned rotl32(unsigned v, int n) {
  return (v << n) | (v >> (32 - n));
}

__host__ __device__ static inline void tf2x32(unsigned k0, unsigned k1,
                                              unsigned x0, unsigned x1,
                                              unsigned* o0, unsigned* o1) {
  unsigned ks0 = k0, ks1 = k1, ks2 = k0 ^ k1 ^ 0x1BD11BDAu;
  x0 += ks0; x1 += ks1;
  const int ra[4] = {13, 15, 26, 6};
  const int rb[4] = {17, 29, 16, 24};
  #pragma unroll
  for (int r = 0; r < 4; ++r) { x0 += x1; x1 = rotl32(x1, ra[r]); x1 ^= x0; }
  x0 += ks1; x1 += ks2 + 1u;
  #pragma unroll
  for (int r = 0; r < 4; ++r) { x0 += x1; x1 = rotl32(x1, rb[r]); x1 ^= x0; }
  x0 += ks2; x1 += ks0 + 2u;
  #pragma unroll
  for (int r = 0; r < 4; ++r) { x0 += x1; x1 = rotl32(x1, ra[r]); x1 ^= x0; }
  x0 += ks0; x1 += ks1 + 3u;
  #pragma unroll
  for (int r = 0; r < 4; ++r) { x0 += x1; x1 = rotl32(x1, rb[r]); x1 ^= x0; }
  x0 += ks1; x1 += ks2 + 4u;
  #pragma unroll
  for (int r = 0; r < 4; ++r) { x0 += x1; x1 = rotl32(x1, ra[r]); x1 ^= x0; }
  x0 += ks2; x1 += ks0 + 5u;
  *o0 = x0; *o1 = x1;
}

// ---------------- init ----------------
__global__ void init_ws_k(int* cnt, float* loss) {
  int t = threadIdx.x;
  if (t < 32) cnt[t] = 0;
  if (t == 32) loss[0] = 0.0f;
}

// ---------------- f32 tiled GEMM: C = A(MxK) @ B(KxN) + bias ----------------
// 64x64 tile, BK=32, 256 threads, 4x4 per thread. Grid: (N/64, M/64).
__global__ __launch_bounds__(256) void gemm_bias_k(
    const float* __restrict__ A, const float* __restrict__ Bm,
    const float* __restrict__ bias, float* __restrict__ C,
    int M, int N, int K) {
  __shared__ float As[32][68];   // [k][row], stride 68 keeps 16B alignment
  __shared__ float Bs[32][68];   // [k][col]
  int tid = threadIdx.x;
  int tx = tid & 15, ty = tid >> 4;
  int row0 = blockIdx.y * 64, col0 = blockIdx.x * 64;
  float acc[4][4] = {};
  int ar = tid >> 3;            // 0..31
  int ac = (tid & 7) * 4;       // 0..28
  int bk = tid >> 4;            // 0..15
  int bc = (tid & 15) * 4;      // 0..60
  const float* Arow0 = A + (size_t)(row0 + ar) * K;
  const float* Arow1 = A + (size_t)(row0 + ar + 32) * K;
  for (int k0 = 0; k0 < K; k0 += 32) {
    float4 va0 = *(const float4*)&Arow0[k0 + ac];
    float4 va1 = *(const float4*)&Arow1[k0 + ac];
    float4 vb0 = *(const float4*)&Bm[(size_t)(k0 + bk) * N + col0 + bc];
    float4 vb1 = *(const float4*)&Bm[(size_t)(k0 + bk + 16) * N + col0 + bc];
    As[ac + 0][ar] = va0.x; As[ac + 1][ar] = va0.y;
    As[ac + 2][ar] = va0.z; As[ac + 3][ar] = va0.w;
    As[ac + 0][ar + 32] = va1.x; As[ac + 1][ar + 32] = va1.y;
    As[ac + 2][ar + 32] = va1.z; As[ac + 3][ar + 32] = va1.w;
    *(float4*)&Bs[bk][bc] = vb0;
    *(float4*)&Bs[bk + 16][bc] = vb1;
    __syncthreads();
    #pragma unroll
    for (int k = 0; k < 32; ++k) {
      float4 a = *(const float4*)&As[k][ty * 4];
      float4 b = *(const float4*)&Bs[k][tx * 4];
      float av[4] = {a.x, a.y, a.z, a.w};
      float bv[4] = {b.x, b.y, b.z, b.w};
      #pragma unroll
      for (int i = 0; i < 4; ++i)
        #pragma unroll
        for (int j = 0; j < 4; ++j)
          acc[i][j] += av[i] * bv[j];
    }
    __syncthreads();
  }
  float4 bv = *(const float4*)&bias[col0 + tx * 4];
  float bb[4] = {bv.x, bv.y, bv.z, bv.w};
  #pragma unroll
  for (int i = 0; i < 4; ++i) {
    size_t rowoff = (size_t)(row0 + ty * 4 + i) * N;
    float4 v = { acc[i][0] + bb[0], acc[i][1] + bb[1],
                 acc[i][2] + bb[2], acc[i][3] + bb[3] };
    *(float4*)&C[rowoff + col0 + tx * 4] = v;
  }
}

// ---------------- gating: per-token top2 + threefry keep + lists ----------------
__global__ __launch_bounds__(64) void gating_k(
    const float* __restrict__ xl, const float* __restrict__ wg,
    int* __restrict__ cnt, int* __restrict__ toklist,
    float* __restrict__ g1o, float* __restrict__ g2o,
    float* __restrict__ loss, unsigned key0, unsigned key1) {
  int b = blockIdx.x;
  int lane = threadIdx.x;
  const float* row = xl + (size_t)b * HD;
  float p[NEXP] = {0, 0, 0, 0, 0, 0};
  for (int d = lane; d < HD; d += 64) {
    float xv = row[d];
    const float* w = wg + (size_t)d * NEXP;
    #pragma unroll
    for (int e = 0; e < NEXP; ++e) p[e] += xv * w[e];
  }
  #pragma unroll
  for (int off = 32; off > 0; off >>= 1)
    #pragma unroll
    for (int e = 0; e < NEXP; ++e) p[e] += __shfl_down(p[e], off);
  if (lane == 0) {
    float mx = p[0];
    #pragma unroll
    for (int e = 1; e < NEXP; ++e) mx = fmaxf(mx, p[e]);
    float ex[NEXP], s = 0.0f;
    #pragma unroll
    for (int e = 0; e < NEXP; ++e) { ex[e] = expf(p[e] - mx); s += ex[e]; }
    float raw[NEXP];
    #pragma unroll
    for (int e = 0; e < NEXP; ++e) raw[e] = ex[e] / s;
    int i1 = 0; float gg1 = raw[0];
    #pragma unroll
    for (int e = 1; e < NEXP; ++e) if (raw[e] > gg1) { gg1 = raw[e]; i1 = e; }
    int i2 = -1; float gg2 = -1.0f;
    #pragma unroll
    for (int e = 0; e < NEXP; ++e) {
      float v = (e == i1) ? 0.0f : raw[e];
      if (v > gg2) { gg2 = v; i2 = e; }
    }
    float den = gg1 + gg2 + 1e-9f;
    float g1n = gg1 / den;
    float g2n = gg2 / den;
    unsigned o0, o1;
    tf2x32(key0, key1, 0u, (unsigned)b, &o0, &o1);
    unsigned bits = o0 ^ o1;
    float prob = __uint_as_float((bits >> 9) | 0x3f800000u) - 1.0f;
    int keep = prob < (g2n / 0.2f);
    int s1 = atomicAdd(&cnt[i1], 1);
    toklist[i1 * MAXR + s1] = b;
    g1o[b] = g1n;
    if (keep) {
      int s2 = atomicAdd(&cnt[i2], 1);
      toklist[i2 * MAXR + s2] = BT + b;
      g2o[b] = g2n;
    } else {
      g2o[b] = 0.0f;
    }
    atomicAdd(loss, gg1);
  }
}

// ---------------- expert GEMM: eo[dest] = relu(x[tok] @ w1[e]) ----------------
// 64x64 tile, BK=32. Grid: (HD/64, MAXR/64, NEXP).
__global__ __launch_bounds__(256) void expert_gemm_k(
    const float* __restrict__ X, const float* __restrict__ W1,
    const int* __restrict__ cnt, const int* __restrict__ toklist,
    float* __restrict__ eo) {
  int e = blockIdx.z;
  int n = cnt[e];
  int row0 = blockIdx.y * 64;
  if (row0 >= n) return;
  const float* Bm = W1 + (size_t)e * HD * HD;
  const int* list = toklist + e * MAXR;
  __shared__ float As[32][68];
  __shared__ float Bs[32][68];
  int tid = threadIdx.x;
  int tx = tid & 15, ty = tid >> 4;
  int col0 = blockIdx.x * 64;
  float acc[4][4] = {};
  int ar = tid >> 3;
  int ac = (tid & 7) * 4;
  int bk = tid >> 4;
  int bc = (tid & 15) * 4;
  int tok0 = (row0 + ar < n) ? (list[row0 + ar] & (BT - 1)) : 0;
  int tok1 = (row0 + ar + 32 < n) ? (list[row0 + ar + 32] & (BT - 1)) : 0;
  const float* Arow0 = X + (size_t)tok0 * HD;
  const float* Arow1 = X + (size_t)tok1 * HD;
  for (int k0 = 0; k0 < HD; k0 += 32) {
    float4 va0 = *(const float4*)&Arow0[k0 + ac];
    float4 va1 = *(const float4*)&Arow1[k0 + ac];
    float4 vb0 = *(const float4*)&Bm[(size_t)(k0 + bk) * HD + col0 + bc];
    float4 vb1 = *(const float4*)&Bm[(size_t)(k0 + bk + 16) * HD + col0 + bc];
    As[ac + 0][ar] = va0.x; As[ac + 1][ar] = va0.y;
    As[ac + 2][ar] = va0.z; As[ac + 3][ar] = va0.w;
    As[ac + 0][ar + 32] = va1.x; As[ac + 1][ar + 32] = va1.y;
    As[ac + 2][ar + 32] = va1.z; As[ac + 3][ar + 32] = va1.w;
    *(float4*)&Bs[bk][bc] = vb0;
    *(float4*)&Bs[bk + 16][bc] = vb1;
    __syncthreads();
    #pragma unroll
    for (int k = 0; k < 32; ++k) {
      float4 a = *(const float4*)&As[k][ty * 4];
      float4 b = *(const float4*)&Bs[k][tx * 4];
      float av[4] = {a.x, a.y, a.z, a.w};
      float bv[4] = {b.x, b.y, b.z, b.w};
      #pragma unroll
      for (int i = 0; i < 4; ++i)
        #pragma unroll
        for (int j = 0; j < 4; ++j)
          acc[i][j] += av[i] * bv[j];
    }
    __syncthreads();
  }
  #pragma unroll
  for (int i = 0; i < 4; ++i) {
    int r = row0 + ty * 4 + i;
    if (r < n) {
      int dest = list[r];
      float4 v = { fmaxf(acc[i][0], 0.0f), fmaxf(acc[i][1], 0.0f),
                   fmaxf(acc[i][2], 0.0f), fmaxf(acc[i][3], 0.0f) };
      *(float4*)&eo[(size_t)dest * HD + col0 + tx * 4] = v;
    }
  }
}

// ---------------- combine (residual + gated expert outputs) + column sums ----------------
__global__ __launch_bounds__(256) void combine_sum_k(
    const float* __restrict__ xl, const float* __restrict__ eo,
    const float* __restrict__ g1o, const float* __restrict__ g2o,
    float* __restrict__ y, float* __restrict__ psum) {
  int c = blockIdx.x * 256 + threadIdx.x;
  int r0 = blockIdx.y * 128;
  float s = 0.0f;
  for (int r = r0; r < r0 + 128; ++r) {
    float v = xl[(size_t)r * HD + c];
    float w1g = g1o[r];
    v += w1g * eo[(size_t)r * HD + c];
    float w2g = g2o[r];
    if (w2g != 0.0f) v += w2g * eo[(size_t)(r + BT) * HD + c];
    y[(size_t)r * HD + c] = v;
    s += v;
  }
  psum[blockIdx.y * HD + c] = s;
}

// ---------------- column sums (for non-MoE BN layers) ----------------
__global__ __launch_bounds__(256) void sum_partial_k(
    const float* __restrict__ src, float* __restrict__ psum) {
  int c = blockIdx.x * 256 + threadIdx.x;
  int r0 = blockIdx.y * 128;
  float s = 0.0f;
  for (int r = r0; r < r0 + 128; ++r) s += src[(size_t)r * HD + c];
  psum[blockIdx.y * HD + c] = s;
}

// ---------------- centered variance partials (two-pass, matches ref) ----------------
__global__ __launch_bounds__(256) void var_partial_k(
    const float* __restrict__ src, const float* __restrict__ psum,
    float* __restrict__ psumsq) {
  int c = blockIdx.x * 256 + threadIdx.x;
  float s = 0.0f;
  #pragma unroll
  for (int i = 0; i < 16; ++i) s += psum[i * HD + c];
  float mu = s * (1.0f / 2048.0f);
  int r0 = blockIdx.y * 128;
  float ss = 0.0f;
  for (int r = r0; r < r0 + 128; ++r) {
    float d = src[(size_t)r * HD + c] - mu;
    ss += d * d;
  }
  psumsq[blockIdx.y * HD + c] = ss;
}

// ---------------- BN apply + relu ----------------
__global__ __launch_bounds__(256) void bn_apply_k(
    const float* __restrict__ src, const float* __restrict__ psum,
    const float* __restrict__ psumsq, const float* __restrict__ gamma,
    const float* __restrict__ beta, float* __restrict__ dst) {
  int c = blockIdx.x * 256 + threadIdx.x;
  float s = 0.0f, ss = 0.0f;
  #pragma unroll
  for (int i = 0; i < 16; ++i) { s += psum[i * HD + c]; ss += psumsq[i * HD + c]; }
  float mu = s * (1.0f / 2048.0f);
  float var = ss * (1.0f / 2048.0f);
  float inv = 1.0f / sqrtf(var + 1e-5f);
  float ga = gamma[c], be = beta[c];
  int r0 = blockIdx.y * 128;
  for (int r = r0; r < r0 + 128; ++r) {
    float v = src[(size_t)r * HD + c];
    float o = ga * (v - mu) * inv + be;
    dst[(size_t)r * HD + c] = fmaxf(o, 0.0f);
  }
}

// ---------------- loss finalize ----------------
__global__ void finalize_loss_k(const float* __restrict__ loss, float* __restrict__ out) {
  if (threadIdx.x == 0) out[BT * 256] = loss[0] * (0.01f * 36.0f / 12288.0f);
}

extern "C" void kernel_launch(void* const* d_in, const int* in_sizes, int n_in,
                              void* d_out, int out_size, void* d_ws, size_t ws_size,
                              hipStream_t stream) {
  const float* x     = (const float*)d_in[0];
  const float* in_W  = (const float*)d_in[1];
  const float* in_b  = (const float*)d_in[2];
  const float* in_g  = (const float*)d_in[3];
  const float* in_be = (const float*)d_in[4];
  const float* sp_W  = (const float*)d_in[5];
  const float* sp_b  = (const float*)d_in[6];
  const float* sp_g  = (const float*)d_in[7];
  const float* sp_be = (const float*)d_in[8];
  const float* sp_gate = (const float*)d_in[9];
  const float* sp_w1 = (const float*)d_in[10];
  const float* dn_W  = (const float*)d_in[11];
  const float* dn_b  = (const float*)d_in[12];
  const float* dn_g  = (const float*)d_in[13];
  const float* dn_be = (const float*)d_in[14];
  const float* out_W = (const float*)d_in[15];
  const float* out_b = (const float*)d_in[16];
  float* out = (float*)d_out;

  float* ws = (float*)d_ws;
  const size_t NEL = (size_t)BT * HD;      // 2M
  float* xl   = ws;
  float* y    = ws + NEL;
  float* h    = ws + 2 * NEL;
  float* eo   = ws + 3 * NEL;              // 4096 x 1024
  float* psum   = ws + 3 * NEL + 2 * NEL;
  float* psumsq = psum + 16 * HD;
  float* g1o  = psumsq + 16 * HD;
  float* g2o  = g1o + BT;
  float* loss = g2o + BT;
  int* cnt    = (int*)(loss + 16);
  int* toklist = cnt + 32;

  unsigned lk0[4], lk1[4];
  for (int i = 0; i < 4; ++i) tf2x32(0u, 42u, 0u, (unsigned)i, &lk0[i], &lk1[i]);

  dim3 blk(256);
  init_ws_k<<<1, 64, 0, stream>>>(cnt, loss);

  // input layer: xl = x @ in_W + in_b ; h = relu(bn(xl))
  gemm_bias_k<<<dim3(16, 32), blk, 0, stream>>>(x, in_W, in_b, xl, BT, HD, 2048);
  sum_partial_k<<<dim3(4, 16), blk, 0, stream>>>(xl, psum);
  var_partial_k<<<dim3(4, 16), blk, 0, stream>>>(xl, psum, psumsq);
  bn_apply_k<<<dim3(4, 16), blk, 0, stream>>>(xl, psum, psumsq, in_g, in_be, h);

  // sparse MoE layers
  for (int i = 0; i < 4; ++i) {
    gemm_bias_k<<<dim3(16, 32), blk, 0, stream>>>(h, sp_W + (size_t)i * HD * HD,
                                                  sp_b + i * HD, xl, BT, HD, HD);
    gating_k<<<BT, 64, 0, stream>>>(xl, sp_gate + (size_t)i * HD * NEXP,
                                    cnt + i * 8, toklist, g1o, g2o, loss,
                                    lk0[i], lk1[i]);
    expert_gemm_k<<<dim3(16, 64, NEXP), blk, 0, stream>>>(
        xl, sp_w1 + (size_t)i * NEXP * HD * HD, cnt + i * 8, toklist, eo);
    combine_sum_k<<<dim3(4, 16), blk, 0, stream>>>(xl, eo, g1o, g2o, y, psum);
    var_partial_k<<<dim3(4, 16), blk, 0, stream>>>(y, psum, psumsq);
    bn_apply_k<<<dim3(4, 16), blk, 0, stream>>>(y, psum, psumsq, sp_g + i * HD,
                                                sp_be + i * HD, h);
  }

  // dense layers
  for (int i = 0; i < 4; ++i) {
    gemm_bias_k<<<dim3(16, 32), blk, 0, stream>>>(h, dn_W + (size_t)i * HD * HD,
                                                  dn_b + i * HD, xl, BT, HD, HD);
    sum_partial_k<<<dim3(4, 16), blk, 0, stream>>>(xl, psum);
    var_partial_k<<<dim3(4, 16), blk, 0, stream>>>(xl, psum, psumsq);
    bn_apply_k<<<dim3(4, 16), blk, 0, stream>>>(xl, psum, psumsq, dn_g + i * HD,
                                                dn_be + i * HD, h);
  }

  // output projection: out = h @ out_W + out_b
  gemm_bias_k<<<dim3(4, 32), blk, 0, stream>>>(h, out_W, out_b, out, BT, 256, HD);
  finalize_loss_k<<<1, 64, 0, stream>>>(loss, out);
}

// Round 3
// 1603.961 us; speedup vs baseline: 2.1281x; 1.3991x over previous
//
#include <hip/hip_runtime.h>

typedef unsigned int uint;
typedef unsigned short ushort;
typedef short bf16x8 __attribute__((ext_vector_type(8)));
typedef ushort ushort8 __attribute__((ext_vector_type(8)));
typedef ushort ushort4v __attribute__((ext_vector_type(4)));
typedef float f32x4 __attribute__((ext_vector_type(4)));

#define HD 1024
#define BT 2048
#define NEXP 6
#define MAXR 4096

// ---------------- bf16 split helpers ----------------
__device__ static inline ushort f32_to_bf16(float f) {
  uint u = __float_as_uint(f);
  u = (u + 0x7fffu + ((u >> 16) & 1u)) >> 16;
  return (ushort)u;
}
__device__ static inline float bf16_to_f32(ushort h) {
  return __uint_as_float(((uint)h) << 16);
}
__device__ static inline void split2(float f, ushort* hi, ushort* lo) {
  ushort h = f32_to_bf16(f);
  *hi = h;
  *lo = f32_to_bf16(f - bf16_to_f32(h));
}

// ---------------- Threefry-2x32 (matches JAX) ----------------
__host__ __device__ static inline unsigned rotl32(unsigned v, int n) {
  return (v << n) | (v >> (32 - n));
}
__host__ __device__ static inline void tf2x32(unsigned k0, unsigned k1,
                                              unsigned x0, unsigned x1,
                                              unsigned* o0, unsigned* o1) {
  unsigned ks0 = k0, ks1 = k1, ks2 = k0 ^ k1 ^ 0x1BD11BDAu;
  x0 += ks0; x1 += ks1;
  const int ra[4] = {13, 15, 26, 6};
  const int rb[4] = {17, 29, 16, 24};
  #pragma unroll
  for (int r = 0; r < 4; ++r) { x0 += x1; x1 = rotl32(x1, ra[r]); x1 ^= x0; }
  x0 += ks1; x1 += ks2 + 1u;
  #pragma unroll
  for (int r = 0; r < 4; ++r) { x0 += x1; x1 = rotl32(x1, rb[r]); x1 ^= x0; }
  x0 += ks2; x1 += ks0 + 2u;
  #pragma unroll
  for (int r = 0; r < 4; ++r) { x0 += x1; x1 = rotl32(x1, ra[r]); x1 ^= x0; }
  x0 += ks0; x1 += ks1 + 3u;
  #pragma unroll
  for (int r = 0; r < 4; ++r) { x0 += x1; x1 = rotl32(x1, rb[r]); x1 ^= x0; }
  x0 += ks1; x1 += ks2 + 4u;
  #pragma unroll
  for (int r = 0; r < 4; ++r) { x0 += x1; x1 = rotl32(x1, ra[r]); x1 ^= x0; }
  x0 += ks2; x1 += ks0 + 5u;
  *o0 = x0; *o1 = x1;
}

// ---------------- init ----------------
__global__ void init_ws_k(int* cnt, float* loss) {
  int t = threadIdx.x;
  if (t < 32) cnt[t] = 0;
  if (t == 32) loss[0] = 0.0f;
}

// ---------------- weight transpose + split: W(K x N) -> Th,Tl (N x K bf16) ----------------
__global__ __launch_bounds__(256) void transpose_split_k(
    const float* __restrict__ W, ushort* __restrict__ Th, ushort* __restrict__ Tl,
    int K, int N) {
  size_t boff = (size_t)blockIdx.z * K * N;
  W += boff; Th += boff; Tl += boff;
  __shared__ float T[32][33];
  int n0 = blockIdx.x * 32, k0 = blockIdx.y * 32;
  int tid = threadIdx.x;
  int r = tid >> 3, c4 = (tid & 7) * 4;
  float4 v = *(const float4*)&W[(size_t)(k0 + r) * N + n0 + c4];
  T[c4 + 0][r] = v.x; T[c4 + 1][r] = v.y; T[c4 + 2][r] = v.z; T[c4 + 3][r] = v.w;
  __syncthreads();
  ushort4v hh, ll;
  #pragma unroll
  for (int j = 0; j < 4; ++j) {
    float f = T[r][c4 + j];
    ushort h, l; split2(f, &h, &l);
    hh[j] = h; ll[j] = l;
  }
  size_t o = (size_t)(n0 + r) * K + k0 + c4;
  *(ushort4v*)&Th[o] = hh;
  *(ushort4v*)&Tl[o] = ll;
}

// ---------------- elementwise split (for input x) ----------------
__global__ __launch_bounds__(256) void split_plain_k(
    const float* __restrict__ X, ushort* __restrict__ Xh, ushort* __restrict__ Xl) {
  size_t i = ((size_t)blockIdx.x * 256 + threadIdx.x) * 4;
  float4 v = *(const float4*)&X[i];
  ushort4v hh, ll;
  float f[4] = {v.x, v.y, v.z, v.w};
  #pragma unroll
  for (int j = 0; j < 4; ++j) { ushort h, l; split2(f[j], &h, &l); hh[j] = h; ll[j] = l; }
  *(ushort4v*)&Xh[i] = hh;
  *(ushort4v*)&Xl[i] = ll;
}

// ---------------- MFMA GEMM: C(MxN) = A(MxK) @ B^T(NxK) [+bias][relu][split] ----------------
// MODE 0: dense + bias -> C f32
// MODE 1: dense + bias -> C f32 + Ch/Cl bf16 split
// MODE 2: expert: gather A rows via list, relu, scatter C rows, no bias; blockIdx.z = expert
template <int MODE>
__global__ __launch_bounds__(256) void gemm_mfma_k(
    const ushort* __restrict__ Ah, const ushort* __restrict__ Al,
    const ushort* __restrict__ Bh, const ushort* __restrict__ Bl,
    const float* __restrict__ bias, float* __restrict__ C,
    ushort* __restrict__ Ch, ushort* __restrict__ Cl,
    const int* __restrict__ cnt, const int* __restrict__ list,
    int N, int K) {
  int nrows = 0;
  if (MODE == 2) {
    int e = blockIdx.z;
    Bh += (size_t)e * N * K;
    Bl += (size_t)e * N * K;
    cnt += e;
    list += e * MAXR;
    nrows = cnt[0];
    if ((int)(blockIdx.y * 128) >= nrows) return;
  }
  __shared__ ushort sAh[128 * 40];
  __shared__ ushort sAl[128 * 40];
  __shared__ ushort sBh[128 * 40];
  __shared__ ushort sBl[128 * 40];
  int tid = threadIdx.x;
  int lane = tid & 63, wave = tid >> 6;
  int wm = (wave >> 1) * 64, wn = (wave & 1) * 64;
  int row0 = blockIdx.y * 128, col0 = blockIdx.x * 128;

  // staging assignment: thread -> one A row + one B row, 2x16B chunks each array
  int srow = tid >> 1;
  int skc = (tid & 1) * 16;
  int swoff = srow * 40 + skc;

  int arow = row0 + srow;
  if (MODE == 2) {
    int d = (arow < nrows) ? list[arow] : 0;
    arow = d & (BT - 1);
  }
  const ushort* pAh = Ah + (size_t)arow * K + skc;
  const ushort* pAl = Al + (size_t)arow * K + skc;
  const ushort* pBh = Bh + (size_t)(col0 + srow) * K + skc;
  const ushort* pBl = Bl + (size_t)(col0 + srow) * K + skc;

  int fr = lane & 15;
  int fk = (lane >> 4) * 8;

  f32x4 acc[4][4] = {};

  for (int k0 = 0; k0 < K; k0 += 32) {
    ushort8 va0 = *(const ushort8*)(pAh + k0);
    ushort8 va1 = *(const ushort8*)(pAh + k0 + 8);
    ushort8 va2 = *(const ushort8*)(pAl + k0);
    ushort8 va3 = *(const ushort8*)(pAl + k0 + 8);
    ushort8 vb0 = *(const ushort8*)(pBh + k0);
    ushort8 vb1 = *(const ushort8*)(pBh + k0 + 8);
    ushort8 vb2 = *(const ushort8*)(pBl + k0);
    ushort8 vb3 = *(const ushort8*)(pBl + k0 + 8);
    __syncthreads();
    *(ushort8*)&sAh[swoff] = va0;
    *(ushort8*)&sAh[swoff + 8] = va1;
    *(ushort8*)&sAl[swoff] = va2;
    *(ushort8*)&sAl[swoff + 8] = va3;
    *(ushort8*)&sBh[swoff] = vb0;
    *(ushort8*)&sBh[swoff + 8] = vb1;
    *(ushort8*)&sBl[swoff] = vb2;
    *(ushort8*)&sBl[swoff + 8] = vb3;
    __syncthreads();
    bf16x8 ah[4], al[4], bh[4], bl[4];
    #pragma unroll
    for (int i = 0; i < 4; ++i) {
      int aoff = (wm + i * 16 + fr) * 40 + fk;
      ah[i] = *(const bf16x8*)&sAh[aoff];
      al[i] = *(const bf16x8*)&sAl[aoff];
      int boff = (wn + i * 16 + fr) * 40 + fk;
      bh[i] = *(const bf16x8*)&sBh[boff];
      bl[i] = *(const bf16x8*)&sBl[boff];
    }
    #pragma unroll
    for (int mi = 0; mi < 4; ++mi)
      #pragma unroll
      for (int ni = 0; ni < 4; ++ni) {
        acc[mi][ni] = __builtin_amdgcn_mfma_f32_16x16x32_bf16(ah[mi], bh[ni], acc[mi][ni], 0, 0, 0);
        acc[mi][ni] = __builtin_amdgcn_mfma_f32_16x16x32_bf16(ah[mi], bl[ni], acc[mi][ni], 0, 0, 0);
        acc[mi][ni] = __builtin_amdgcn_mfma_f32_16x16x32_bf16(al[mi], bh[ni], acc[mi][ni], 0, 0, 0);
      }
  }

  // epilogue: C/D layout col = lane&15, row = (lane>>4)*4 + reg
  if (MODE == 2) {
    #pragma unroll
    for (int mi = 0; mi < 4; ++mi) {
      int rbase = row0 + wm + mi * 16 + (lane >> 4) * 4;
      #pragma unroll
      for (int r = 0; r < 4; ++r) {
        int row = rbase + r;
        if (row < nrows) {
          size_t drow = (size_t)list[row] * N;
          #pragma unroll
          for (int ni = 0; ni < 4; ++ni) {
            int col = col0 + wn + ni * 16 + fr;
            C[drow + col] = fmaxf(acc[mi][ni][r], 0.0f);
          }
        }
      }
    }
  } else {
    float bv[4];
    #pragma unroll
    for (int ni = 0; ni < 4; ++ni) bv[ni] = bias[col0 + wn + ni * 16 + fr];
    #pragma unroll
    for (int mi = 0; mi < 4; ++mi) {
      int rbase = row0 + wm + mi * 16 + (lane >> 4) * 4;
      #pragma unroll
      for (int r = 0; r < 4; ++r) {
        size_t rowoff = (size_t)(rbase + r) * N;
        #pragma unroll
        for (int ni = 0; ni < 4; ++ni) {
          int col = col0 + wn + ni * 16 + fr;
          float v = acc[mi][ni][r] + bv[ni];
          C[rowoff + col] = v;
          if (MODE == 1) {
            ushort h, l; split2(v, &h, &l);
            Ch[rowoff + col] = h;
            Cl[rowoff + col] = l;
          }
        }
      }
    }
  }
}

// ---------------- gating ----------------
__global__ __launch_bounds__(64) void gating_k(
    const float* __restrict__ xl, const float* __restrict__ wg,
    int* __restrict__ cnt, int* __restrict__ toklist,
    float* __restrict__ g1o, float* __restrict__ g2o,
    float* __restrict__ loss, unsigned key0, unsigned key1) {
  int b = blockIdx.x;
  int lane = threadIdx.x;
  const float* row = xl + (size_t)b * HD;
  float p[NEXP] = {0, 0, 0, 0, 0, 0};
  for (int d = lane; d < HD; d += 64) {
    float xv = row[d];
    const float* w = wg + (size_t)d * NEXP;
    #pragma unroll
    for (int e = 0; e < NEXP; ++e) p[e] += xv * w[e];
  }
  #pragma unroll
  for (int off = 32; off > 0; off >>= 1)
    #pragma unroll
    for (int e = 0; e < NEXP; ++e) p[e] += __shfl_down(p[e], off);
  if (lane == 0) {
    float mx = p[0];
    #pragma unroll
    for (int e = 1; e < NEXP; ++e) mx = fmaxf(mx, p[e]);
    float ex[NEXP], s = 0.0f;
    #pragma unroll
    for (int e = 0; e < NEXP; ++e) { ex[e] = expf(p[e] - mx); s += ex[e]; }
    float raw[NEXP];
    #pragma unroll
    for (int e = 0; e < NEXP; ++e) raw[e] = ex[e] / s;
    int i1 = 0; float gg1 = raw[0];
    #pragma unroll
    for (int e = 1; e < NEXP; ++e) if (raw[e] > gg1) { gg1 = raw[e]; i1 = e; }
    int i2 = -1; float gg2 = -1.0f;
    #pragma unroll
    for (int e = 0; e < NEXP; ++e) {
      float v = (e == i1) ? 0.0f : raw[e];
      if (v > gg2) { gg2 = v; i2 = e; }
    }
    float den = gg1 + gg2 + 1e-9f;
    float g1n = gg1 / den;
    float g2n = gg2 / den;
    unsigned o0, o1;
    tf2x32(key0, key1, 0u, (unsigned)b, &o0, &o1);
    unsigned bits = o0 ^ o1;
    float prob = __uint_as_float((bits >> 9) | 0x3f800000u) - 1.0f;
    int keep = prob < (g2n / 0.2f);
    int s1 = atomicAdd(&cnt[i1], 1);
    toklist[i1 * MAXR + s1] = b;
    g1o[b] = g1n;
    if (keep) {
      int s2 = atomicAdd(&cnt[i2], 1);
      toklist[i2 * MAXR + s2] = BT + b;
      g2o[b] = g2n;
    } else {
      g2o[b] = 0.0f;
    }
    atomicAdd(loss, gg1);
  }
}

// ---------------- combine + column partial sums (32 slices) ----------------
__global__ __launch_bounds__(256) void combine_sum_k(
    const float* __restrict__ xl, const float* __restrict__ eo,
    const float* __restrict__ g1o, const float* __restrict__ g2o,
    float* __restrict__ y, float* __restrict__ psum) {
  int c = blockIdx.x * 256 + threadIdx.x;
  int r0 = blockIdx.y * 64;
  float s = 0.0f;
  for (int r = r0; r < r0 + 64; ++r) {
    float v = xl[(size_t)r * HD + c];
    float w1g = g1o[r];
    v += w1g * eo[(size_t)r * HD + c];
    float w2g = g2o[r];
    if (w2g != 0.0f) v += w2g * eo[(size_t)(r + BT) * HD + c];
    y[(size_t)r * HD + c] = v;
    s += v;
  }
  psum[blockIdx.y * HD + c] = s;
}

__global__ __launch_bounds__(256) void sum_partial_k(
    const float* __restrict__ src, float* __restrict__ psum) {
  int c = blockIdx.x * 256 + threadIdx.x;
  int r0 = blockIdx.y * 64;
  float s = 0.0f;
  for (int r = r0; r < r0 + 64; ++r) s += src[(size_t)r * HD + c];
  psum[blockIdx.y * HD + c] = s;
}

__global__ __launch_bounds__(256) void var_partial_k(
    const float* __restrict__ src, const float* __restrict__ psum,
    float* __restrict__ psumsq) {
  int c = blockIdx.x * 256 + threadIdx.x;
  float s = 0.0f;
  #pragma unroll
  for (int i = 0; i < 32; ++i) s += psum[i * HD + c];
  float mu = s * (1.0f / 2048.0f);
  int r0 = blockIdx.y * 64;
  float ss = 0.0f;
  for (int r = r0; r < r0 + 64; ++r) {
    float d = src[(size_t)r * HD + c] - mu;
    ss += d * d;
  }
  psumsq[blockIdx.y * HD + c] = ss;
}

// ---------------- BN apply + relu -> bf16 hi/lo split ----------------
__global__ __launch_bounds__(256) void bn_split_k(
    const float* __restrict__ src, const float* __restrict__ psum,
    const float* __restrict__ psumsq, const float* __restrict__ gamma,
    const float* __restrict__ beta, ushort* __restrict__ Hh,
    ushort* __restrict__ Hl) {
  int c = blockIdx.x * 256 + threadIdx.x;
  float s = 0.0f, ss = 0.0f;
  #pragma unroll
  for (int i = 0; i < 32; ++i) { s += psum[i * HD + c]; ss += psumsq[i * HD + c]; }
  float mu = s * (1.0f / 2048.0f);
  float var = ss * (1.0f / 2048.0f);
  float inv = 1.0f / sqrtf(var + 1e-5f);
  float ga = gamma[c], be = beta[c];
  int r0 = blockIdx.y * 64;
  for (int r = r0; r < r0 + 64; ++r) {
    float v = src[(size_t)r * HD + c];
    float o = fmaxf(ga * (v - mu) * inv + be, 0.0f);
    ushort h, l; split2(o, &h, &l);
    Hh[(size_t)r * HD + c] = h;
    Hl[(size_t)r * HD + c] = l;
  }
}

// ---------------- loss finalize ----------------
__global__ void finalize_loss_k(const float* __restrict__ loss, float* __restrict__ out) {
  if (threadIdx.x == 0) out[BT * 256] = loss[0] * (0.01f * 36.0f / 12288.0f);
}

extern "C" void kernel_launch(void* const* d_in, const int* in_sizes, int n_in,
                              void* d_out, int out_size, void* d_ws, size_t ws_size,
                              hipStream_t stream) {
  const float* x     = (const float*)d_in[0];
  const float* in_W  = (const float*)d_in[1];
  const float* in_b  = (const float*)d_in[2];
  const float* in_g  = (const float*)d_in[3];
  const float* in_be = (const float*)d_in[4];
  const float* sp_W  = (const float*)d_in[5];
  const float* sp_b  = (const float*)d_in[6];
  const float* sp_g  = (const float*)d_in[7];
  const float* sp_be = (const float*)d_in[8];
  const float* sp_gate = (const float*)d_in[9];
  const float* sp_w1 = (const float*)d_in[10];
  const float* dn_W  = (const float*)d_in[11];
  const float* dn_b  = (const float*)d_in[12];
  const float* dn_g  = (const float*)d_in[13];
  const float* dn_be = (const float*)d_in[14];
  const float* out_W = (const float*)d_in[15];
  const float* out_b = (const float*)d_in[16];
  float* out = (float*)d_out;

  // ---- workspace layout (bytes) ----
  char* base = (char*)d_ws;
  size_t off = 0;
  auto alloc = [&](size_t bytes) { void* p = base + off; off = (off + bytes + 255) & ~(size_t)255; return p; };
  float*  xl     = (float*)alloc((size_t)BT * HD * 4);
  float*  y      = (float*)alloc((size_t)BT * HD * 4);
  float*  eo     = (float*)alloc((size_t)MAXR * HD * 4);
  float*  psum   = (float*)alloc(32 * HD * 4);
  float*  psumsq = (float*)alloc(32 * HD * 4);
  float*  g1o    = (float*)alloc(BT * 4);
  float*  g2o    = (float*)alloc(BT * 4);
  float*  loss   = (float*)alloc(256);
  int*    cnt    = (int*)alloc(256);
  int*    toklist= (int*)alloc(NEXP * MAXR * 4);
  ushort* Hh     = (ushort*)alloc((size_t)BT * HD * 2);
  ushort* Hl     = (ushort*)alloc((size_t)BT * HD * 2);
  ushort* Xh     = (ushort*)alloc((size_t)BT * 2048 * 2);
  ushort* Xl     = (ushort*)alloc((size_t)BT * 2048 * 2);
  ushort* XLh    = (ushort*)alloc((size_t)BT * HD * 2);
  ushort* XLl    = (ushort*)alloc((size_t)BT * HD * 2);
  ushort* inWTh  = (ushort*)alloc((size_t)2048 * HD * 2);
  ushort* inWTl  = (ushort*)alloc((size_t)2048 * HD * 2);
  ushort* spWTh  = (ushort*)alloc((size_t)4 * HD * HD * 2);
  ushort* spWTl  = (ushort*)alloc((size_t)4 * HD * HD * 2);
  ushort* w1Th   = (ushort*)alloc((size_t)24 * HD * HD * 2);
  ushort* w1Tl   = (ushort*)alloc((size_t)24 * HD * HD * 2);
  ushort* dnWTh  = (ushort*)alloc((size_t)4 * HD * HD * 2);
  ushort* dnWTl  = (ushort*)alloc((size_t)4 * HD * HD * 2);
  ushort* outWTh = (ushort*)alloc((size_t)HD * 256 * 2);
  ushort* outWTl = (ushort*)alloc((size_t)HD * 256 * 2);

  unsigned lk0[4], lk1[4];
  for (int i = 0; i < 4; ++i) tf2x32(0u, 42u, 0u, (unsigned)i, &lk0[i], &lk1[i]);

  dim3 blk(256);
  init_ws_k<<<1, 64, 0, stream>>>(cnt, loss);

  // ---- weight prep (transpose + bf16 split) ----
  transpose_split_k<<<dim3(32, 64, 1), blk, 0, stream>>>(in_W, inWTh, inWTl, 2048, HD);
  transpose_split_k<<<dim3(32, 32, 4), blk, 0, stream>>>(sp_W, spWTh, spWTl, HD, HD);
  transpose_split_k<<<dim3(32, 32, 24), blk, 0, stream>>>(sp_w1, w1Th, w1Tl, HD, HD);
  transpose_split_k<<<dim3(32, 32, 4), blk, 0, stream>>>(dn_W, dnWTh, dnWTl, HD, HD);
  transpose_split_k<<<dim3(8, 32, 1), blk, 0, stream>>>(out_W, outWTh, outWTl, HD, 256);
  split_plain_k<<<(BT * 2048) / 1024, blk, 0, stream>>>(x, Xh, Xl);

  // ---- input layer ----
  gemm_mfma_k<0><<<dim3(8, 16), blk, 0, stream>>>(Xh, Xl, inWTh, inWTl, in_b, xl,
                                                  nullptr, nullptr, nullptr, nullptr, HD, 2048);
  sum_partial_k<<<dim3(4, 32), blk, 0, stream>>>(xl, psum);
  var_partial_k<<<dim3(4, 32), blk, 0, stream>>>(xl, psum, psumsq);
  bn_split_k<<<dim3(4, 32), blk, 0, stream>>>(xl, psum, psumsq, in_g, in_be, Hh, Hl);

  // ---- sparse MoE layers ----
  for (int i = 0; i < 4; ++i) {
    gemm_mfma_k<1><<<dim3(8, 16), blk, 0, stream>>>(Hh, Hl, spWTh + (size_t)i * HD * HD,
                                                    spWTl + (size_t)i * HD * HD, sp_b + i * HD,
                                                    xl, XLh, XLl, nullptr, nullptr, HD, HD);
    gating_k<<<BT, 64, 0, stream>>>(xl, sp_gate + (size_t)i * HD * NEXP,
                                    cnt + i * 8, toklist, g1o, g2o, loss, lk0[i], lk1[i]);
    gemm_mfma_k<2><<<dim3(8, 32, NEXP), blk, 0, stream>>>(XLh, XLl,
                                                          w1Th + (size_t)i * NEXP * HD * HD,
                                                          w1Tl + (size_t)i * NEXP * HD * HD,
                                                          nullptr, eo, nullptr, nullptr,
                                                          cnt + i * 8, toklist, HD, HD);
    combine_sum_k<<<dim3(4, 32), blk, 0, stream>>>(xl, eo, g1o, g2o, y, psum);
    var_partial_k<<<dim3(4, 32), blk, 0, stream>>>(y, psum, psumsq);
    bn_split_k<<<dim3(4, 32), blk, 0, stream>>>(y, psum, psumsq, sp_g + i * HD,
                                                sp_be + i * HD, Hh, Hl);
  }

  // ---- dense layers ----
  for (int i = 0; i < 4; ++i) {
    gemm_mfma_k<0><<<dim3(8, 16), blk, 0, stream>>>(Hh, Hl, dnWTh + (size_t)i * HD * HD,
                                                    dnWTl + (size_t)i * HD * HD, dn_b + i * HD,
                                                    xl, nullptr, nullptr, nullptr, nullptr, HD, HD);
    sum_partial_k<<<dim3(4, 32), blk, 0, stream>>>(xl, psum);
    var_partial_k<<<dim3(4, 32), blk, 0, stream>>>(xl, psum, psumsq);
    bn_split_k<<<dim3(4, 32), blk, 0, stream>>>(xl, psum, psumsq, dn_g + i * HD,
                                                dn_be + i * HD, Hh, Hl);
  }

  // ---- output projection ----
  gemm_mfma_k<0><<<dim3(2, 16), blk, 0, stream>>>(Hh, Hl, outWTh, outWTl, out_b, out,
                                                  nullptr, nullptr, nullptr, nullptr, 256, HD);
  finalize_loss_k<<<1, 64, 0, stream>>>(loss, out);
}

// Round 4
// 1380.636 us; speedup vs baseline: 2.4724x; 1.1618x over previous
//
#include <hip/hip_runtime.h>

typedef unsigned int uint;
typedef unsigned short ushort;
typedef short bf16x8 __attribute__((ext_vector_type(8)));
typedef ushort ushort4v __attribute__((ext_vector_type(4)));
typedef float f32x4 __attribute__((ext_vector_type(4)));

#define HD 1024
#define BT 2048
#define NEXP 6
#define MAXR 4096

typedef __attribute__((address_space(1))) void as1_void;
typedef __attribute__((address_space(3))) void as3_void;
#define ASYNC16(g, l) \
  __builtin_amdgcn_global_load_lds((as1_void*)(const void*)(g), (as3_void*)(void*)(l), 16, 0, 0)

// ---------------- bf16 split helpers ----------------
__device__ static inline ushort f32_to_bf16(float f) {
  uint u = __float_as_uint(f);
  u = (u + 0x7fffu + ((u >> 16) & 1u)) >> 16;
  return (ushort)u;
}
__device__ static inline float bf16_to_f32(ushort h) {
  return __uint_as_float(((uint)h) << 16);
}
__device__ static inline void split2(float f, ushort* hi, ushort* lo) {
  ushort h = f32_to_bf16(f);
  *hi = h;
  *lo = f32_to_bf16(f - bf16_to_f32(h));
}

// ---------------- Threefry-2x32 (matches JAX) ----------------
__host__ __device__ static inline unsigned rotl32(unsigned v, int n) {
  return (v << n) | (v >> (32 - n));
}
__host__ __device__ static inline void tf2x32(unsigned k0, unsigned k1,
                                              unsigned x0, unsigned x1,
                                              unsigned* o0, unsigned* o1) {
  unsigned ks0 = k0, ks1 = k1, ks2 = k0 ^ k1 ^ 0x1BD11BDAu;
  x0 += ks0; x1 += ks1;
  const int ra[4] = {13, 15, 26, 6};
  const int rb[4] = {17, 29, 16, 24};
  #pragma unroll
  for (int r = 0; r < 4; ++r) { x0 += x1; x1 = rotl32(x1, ra[r]); x1 ^= x0; }
  x0 += ks1; x1 += ks2 + 1u;
  #pragma unroll
  for (int r = 0; r < 4; ++r) { x0 += x1; x1 = rotl32(x1, rb[r]); x1 ^= x0; }
  x0 += ks2; x1 += ks0 + 2u;
  #pragma unroll
  for (int r = 0; r < 4; ++r) { x0 += x1; x1 = rotl32(x1, ra[r]); x1 ^= x0; }
  x0 += ks0; x1 += ks1 + 3u;
  #pragma unroll
  for (int r = 0; r < 4; ++r) { x0 += x1; x1 = rotl32(x1, rb[r]); x1 ^= x0; }
  x0 += ks1; x1 += ks2 + 4u;
  #pragma unroll
  for (int r = 0; r < 4; ++r) { x0 += x1; x1 = rotl32(x1, ra[r]); x1 ^= x0; }
  x0 += ks2; x1 += ks0 + 5u;
  *o0 = x0; *o1 = x1;
}

// ---------------- init ----------------
__global__ void init_ws_k(int* cnt, float* loss) {
  int t = threadIdx.x;
  if (t < 32) cnt[t] = 0;
  if (t == 32) loss[0] = 0.0f;
}

// ---------------- weight transpose + split: W(K x N) -> Th,Tl (N x K bf16) ----------------
__global__ __launch_bounds__(256) void transpose_split_k(
    const float* __restrict__ W, ushort* __restrict__ Th, ushort* __restrict__ Tl,
    int K, int N) {
  size_t boff = (size_t)blockIdx.z * K * N;
  W += boff; Th += boff; Tl += boff;
  __shared__ float T[32][33];
  int n0 = blockIdx.x * 32, k0 = blockIdx.y * 32;
  int tid = threadIdx.x;
  int r = tid >> 3, c4 = (tid & 7) * 4;
  float4 v = *(const float4*)&W[(size_t)(k0 + r) * N + n0 + c4];
  T[c4 + 0][r] = v.x; T[c4 + 1][r] = v.y; T[c4 + 2][r] = v.z; T[c4 + 3][r] = v.w;
  __syncthreads();
  ushort4v hh, ll;
  #pragma unroll
  for (int j = 0; j < 4; ++j) {
    float f = T[r][c4 + j];
    ushort h, l; split2(f, &h, &l);
    hh[j] = h; ll[j] = l;
  }
  size_t o = (size_t)(n0 + r) * K + k0 + c4;
  *(ushort4v*)&Th[o] = hh;
  *(ushort4v*)&Tl[o] = ll;
}

// ---------------- elementwise split (for input x) ----------------
__global__ __launch_bounds__(256) void split_plain_k(
    const float* __restrict__ X, ushort* __restrict__ Xh, ushort* __restrict__ Xl) {
  size_t i = ((size_t)blockIdx.x * 256 + threadIdx.x) * 4;
  float4 v = *(const float4*)&X[i];
  ushort4v hh, ll;
  float f[4] = {v.x, v.y, v.z, v.w};
  #pragma unroll
  for (int j = 0; j < 4; ++j) { ushort h, l; split2(f[j], &h, &l); hh[j] = h; ll[j] = l; }
  *(ushort4v*)&Xh[i] = hh;
  *(ushort4v*)&Xl[i] = ll;
}

// ---------------- MFMA GEMM, async-staged, swizzled LDS, split-K ----------------
// MODE 0: C_partial[z] = A @ B^T slice-of-K (no bias, raw f32 partial)
// MODE 2: expert: gather A rows via list, full K, relu, scatter C rows; z = expert
template <int MODE>
__global__ __launch_bounds__(256) void gemm_mfma_k(
    const ushort* __restrict__ Ah, const ushort* __restrict__ Al,
    const ushort* __restrict__ Bh, const ushort* __restrict__ Bl,
    float* __restrict__ P,
    const int* __restrict__ cnt, const int* __restrict__ list,
    int N, int K, int ksteps) {
  int bz = blockIdx.z;
  int row0 = blockIdx.y * 128, col0 = blockIdx.x * 128;
  int nrows = 0, kbase = 0;
  if (MODE == 2) {
    size_t wo = (size_t)bz * N * K;
    Bh += wo; Bl += wo;
    nrows = cnt[bz];
    list += bz * MAXR;
    if (row0 >= nrows) return;
  } else {
    P += (size_t)bz * BT * N;
    kbase = bz * ksteps * 32;
  }
  __shared__ ushort sAh[4096], sAl[4096], sBh[4096], sBl[4096];
  int tid = threadIdx.x;
  int lane = tid & 63, w = tid >> 6;
  int wm = (w >> 1) * 64, wn = (w & 1) * 64;

  // staging: per thread 2 chunks (16B) per array; chunk slot XOR-swizzled by row
  const ushort *pAh[2], *pAl[2], *pBh[2], *pBl[2];
  #pragma unroll
  for (int j = 0; j < 2; ++j) {
    int ci = j * 256 + tid;
    int r = ci >> 2;
    int cl = (ci & 3) ^ ((r ^ (r >> 2)) & 3);
    int ra = row0 + r;
    if (MODE == 2) ra = (ra < nrows) ? (list[ra] & (BT - 1)) : 0;
    size_t ao = (size_t)ra * K + kbase + cl * 8;
    size_t bo = (size_t)(col0 + r) * K + kbase + cl * 8;
    pAh[j] = Ah + ao; pAl[j] = Al + ao;
    pBh[j] = Bh + bo; pBl[j] = Bl + bo;
  }
  int lb0 = w * 512, lb1 = 2048 + w * 512;  // ushort offsets, wave-uniform

  // fragment LDS offsets (swizzled to match staging)
  int fr = lane & 15, cq = lane >> 4;
  int offA[4], offB[4];
  #pragma unroll
  for (int i = 0; i < 4; ++i) {
    int rA = wm + i * 16 + fr;
    offA[i] = rA * 32 + (cq ^ ((rA ^ (rA >> 2)) & 3)) * 8;
    int rB = wn + i * 16 + fr;
    offB[i] = rB * 32 + (cq ^ ((rB ^ (rB >> 2)) & 3)) * 8;
  }

  f32x4 acc[4][4] = {};

  for (int ks = 0; ks < ksteps; ++ks) {
    int ko = ks * 32;
    __syncthreads();
    ASYNC16(pAh[0] + ko, sAh + lb0);
    ASYNC16(pAh[1] + ko, sAh + lb1);
    ASYNC16(pAl[0] + ko, sAl + lb0);
    ASYNC16(pAl[1] + ko, sAl + lb1);
    ASYNC16(pBh[0] + ko, sBh + lb0);
    ASYNC16(pBh[1] + ko, sBh + lb1);
    ASYNC16(pBl[0] + ko, sBl + lb0);
    ASYNC16(pBl[1] + ko, sBl + lb1);
    __syncthreads();
    bf16x8 ah[4], al[4], bh[4], bl[4];
    #pragma unroll
    for (int i = 0; i < 4; ++i) {
      ah[i] = *(const bf16x8*)&sAh[offA[i]];
      al[i] = *(const bf16x8*)&sAl[offA[i]];
      bh[i] = *(const bf16x8*)&sBh[offB[i]];
      bl[i] = *(const bf16x8*)&sBl[offB[i]];
    }
    #pragma unroll
    for (int mi = 0; mi < 4; ++mi)
      #pragma unroll
      for (int ni = 0; ni < 4; ++ni) {
        acc[mi][ni] = __builtin_amdgcn_mfma_f32_16x16x32_bf16(ah[mi], bh[ni], acc[mi][ni], 0, 0, 0);
        acc[mi][ni] = __builtin_amdgcn_mfma_f32_16x16x32_bf16(ah[mi], bl[ni], acc[mi][ni], 0, 0, 0);
        acc[mi][ni] = __builtin_amdgcn_mfma_f32_16x16x32_bf16(al[mi], bh[ni], acc[mi][ni], 0, 0, 0);
      }
  }

  // epilogue: C/D layout col = lane&15, row = (lane>>4)*4 + reg
  if (MODE == 2) {
    #pragma unroll
    for (int mi = 0; mi < 4; ++mi) {
      int rb = row0 + wm + mi * 16 + cq * 4;
      #pragma unroll
      for (int r = 0; r < 4; ++r) {
        int row = rb + r;
        if (row < nrows) {
          size_t dro = (size_t)list[row] * N;
          #pragma unroll
          for (int ni = 0; ni < 4; ++ni)
            P[dro + col0 + wn + ni * 16 + fr] = fmaxf(acc[mi][ni][r], 0.0f);
        }
      }
    }
  } else {
    #pragma unroll
    for (int mi = 0; mi < 4; ++mi) {
      int rb = row0 + wm + mi * 16 + cq * 4;
      #pragma unroll
      for (int r = 0; r < 4; ++r) {
        size_t ro = (size_t)(rb + r) * N;
        #pragma unroll
        for (int ni = 0; ni < 4; ++ni)
          P[ro + col0 + wn + ni * 16 + fr] = acc[mi][ni][r];
      }
    }
  }
}

// ---------------- split-K reduce + bias -> xl f32, + BN column partial sums ----------------
template <int NS>
__global__ __launch_bounds__(256) void reduce_dense_k(
    const float* __restrict__ P, const float* __restrict__ bias,
    float* __restrict__ xl, float* __restrict__ psum) {
  int c = blockIdx.x * 256 + threadIdx.x;
  int r0 = blockIdx.y * 64;
  float bv = bias[c];
  float s = 0.0f;
  for (int r = r0; r < r0 + 64; ++r) {
    float v = bv;
    #pragma unroll
    for (int j = 0; j < NS; ++j) v += P[(size_t)j * BT * HD + (size_t)r * HD + c];
    xl[(size_t)r * HD + c] = v;
    s += v;
  }
  psum[blockIdx.y * HD + c] = s;
}

// ---------------- split-K reduce + bias -> xl f32 + bf16 hi/lo (MoE input) ----------------
template <int NS>
__global__ __launch_bounds__(256) void reduce_split_k(
    const float* __restrict__ P, const float* __restrict__ bias,
    float* __restrict__ xl, ushort* __restrict__ Xh, ushort* __restrict__ Xl2) {
  int c = blockIdx.x * 256 + threadIdx.x;
  int r0 = blockIdx.y * 64;
  float bv = bias[c];
  for (int r = r0; r < r0 + 64; ++r) {
    float v = bv;
    #pragma unroll
    for (int j = 0; j < NS; ++j) v += P[(size_t)j * BT * HD + (size_t)r * HD + c];
    xl[(size_t)r * HD + c] = v;
    ushort h, l; split2(v, &h, &l);
    Xh[(size_t)r * HD + c] = h;
    Xl2[(size_t)r * HD + c] = l;
  }
}

// ---------------- output reduce: out = sum P + bias ----------------
__global__ __launch_bounds__(256) void reduce_out_k(
    const float* __restrict__ P, const float* __restrict__ bias,
    float* __restrict__ out) {
  int c = threadIdx.x;
  int r0 = blockIdx.y * 64;
  float bv = bias[c];
  for (int r = r0; r < r0 + 64; ++r) {
    float v = bv;
    #pragma unroll
    for (int j = 0; j < 8; ++j) v += P[(size_t)j * BT * 256 + (size_t)r * 256 + c];
    out[(size_t)r * 256 + c] = v;
  }
}

// ---------------- gating ----------------
__global__ __launch_bounds__(64) void gating_k(
    const float* __restrict__ xl, const float* __restrict__ wg,
    int* __restrict__ cnt, int* __restrict__ toklist,
    float* __restrict__ g1o, float* __restrict__ g2o,
    float* __restrict__ loss, unsigned key0, unsigned key1) {
  int b = blockIdx.x;
  int lane = threadIdx.x;
  const float* row = xl + (size_t)b * HD;
  float p[NEXP] = {0, 0, 0, 0, 0, 0};
  for (int d = lane; d < HD; d += 64) {
    float xv = row[d];
    const float* w = wg + (size_t)d * NEXP;
    #pragma unroll
    for (int e = 0; e < NEXP; ++e) p[e] += xv * w[e];
  }
  #pragma unroll
  for (int off = 32; off > 0; off >>= 1)
    #pragma unroll
    for (int e = 0; e < NEXP; ++e) p[e] += __shfl_down(p[e], off);
  if (lane == 0) {
    float mx = p[0];
    #pragma unroll
    for (int e = 1; e < NEXP; ++e) mx = fmaxf(mx, p[e]);
    float ex[NEXP], s = 0.0f;
    #pragma unroll
    for (int e = 0; e < NEXP; ++e) { ex[e] = expf(p[e] - mx); s += ex[e]; }
    float raw[NEXP];
    #pragma unroll
    for (int e = 0; e < NEXP; ++e) raw[e] = ex[e] / s;
    int i1 = 0; float gg1 = raw[0];
    #pragma unroll
    for (int e = 1; e < NEXP; ++e) if (raw[e] > gg1) { gg1 = raw[e]; i1 = e; }
    int i2 = -1; float gg2 = -1.0f;
    #pragma unroll
    for (int e = 0; e < NEXP; ++e) {
      float v = (e == i1) ? 0.0f : raw[e];
      if (v > gg2) { gg2 = v; i2 = e; }
    }
    float den = gg1 + gg2 + 1e-9f;
    float g1n = gg1 / den;
    float g2n = gg2 / den;
    unsigned o0, o1;
    tf2x32(key0, key1, 0u, (unsigned)b, &o0, &o1);
    unsigned bits = o0 ^ o1;
    float prob = __uint_as_float((bits >> 9) | 0x3f800000u) - 1.0f;
    int keep = prob < (g2n / 0.2f);
    int s1 = atomicAdd(&cnt[i1], 1);
    toklist[i1 * MAXR + s1] = b;
    g1o[b] = g1n;
    if (keep) {
      int s2 = atomicAdd(&cnt[i2], 1);
      toklist[i2 * MAXR + s2] = BT + b;
      g2o[b] = g2n;
    } else {
      g2o[b] = 0.0f;
    }
    atomicAdd(loss, gg1);
  }
}

// ---------------- combine + column partial sums ----------------
__global__ __launch_bounds__(256) void combine_sum_k(
    const float* __restrict__ xl, const float* __restrict__ eo,
    const float* __restrict__ g1o, const float* __restrict__ g2o,
    float* __restrict__ y, float* __restrict__ psum) {
  int c = blockIdx.x * 256 + threadIdx.x;
  int r0 = blockIdx.y * 64;
  float s = 0.0f;
  for (int r = r0; r < r0 + 64; ++r) {
    float v = xl[(size_t)r * HD + c];
    float w1g = g1o[r];
    v += w1g * eo[(size_t)r * HD + c];
    float w2g = g2o[r];
    if (w2g != 0.0f) v += w2g * eo[(size_t)(r + BT) * HD + c];
    y[(size_t)r * HD + c] = v;
    s += v;
  }
  psum[blockIdx.y * HD + c] = s;
}

__global__ __launch_bounds__(256) void var_partial_k(
    const float* __restrict__ src, const float* __restrict__ psum,
    float* __restrict__ psumsq) {
  int c = blockIdx.x * 256 + threadIdx.x;
  float s = 0.0f;
  #pragma unroll
  for (int i = 0; i < 32; ++i) s += psum[i * HD + c];
  float mu = s * (1.0f / 2048.0f);
  int r0 = blockIdx.y * 64;
  float ss = 0.0f;
  for (int r = r0; r < r0 + 64; ++r) {
    float d = src[(size_t)r * HD + c] - mu;
    ss += d * d;
  }
  psumsq[blockIdx.y * HD + c] = ss;
}

// ---------------- BN apply + relu -> bf16 hi/lo split ----------------
__global__ __launch_bounds__(256) void bn_split_k(
    const float* __restrict__ src, const float* __restrict__ psum,
    const float* __restrict__ psumsq, const float* __restrict__ gamma,
    const float* __restrict__ beta, ushort* __restrict__ Hh,
    ushort* __restrict__ Hl) {
  int c = blockIdx.x * 256 + threadIdx.x;
  float s = 0.0f, ss = 0.0f;
  #pragma unroll
  for (int i = 0; i < 32; ++i) { s += psum[i * HD + c]; ss += psumsq[i * HD + c]; }
  float mu = s * (1.0f / 2048.0f);
  float var = ss * (1.0f / 2048.0f);
  float inv = 1.0f / sqrtf(var + 1e-5f);
  float ga = gamma[c], be = beta[c];
  int r0 = blockIdx.y * 64;
  for (int r = r0; r < r0 + 64; ++r) {
    float v = src[(size_t)r * HD + c];
    float o = fmaxf(ga * (v - mu) * inv + be, 0.0f);
    ushort h, l; split2(o, &h, &l);
    Hh[(size_t)r * HD + c] = h;
    Hl[(size_t)r * HD + c] = l;
  }
}

// ---------------- loss finalize ----------------
__global__ void finalize_loss_k(const float* __restrict__ loss, float* __restrict__ out) {
  if (threadIdx.x == 0) out[BT * 256] = loss[0] * (0.01f * 36.0f / 12288.0f);
}

extern "C" void kernel_launch(void* const* d_in, const int* in_sizes, int n_in,
                              void* d_out, int out_size, void* d_ws, size_t ws_size,
                              hipStream_t stream) {
  const float* x     = (const float*)d_in[0];
  const float* in_W  = (const float*)d_in[1];
  const float* in_b  = (const float*)d_in[2];
  const float* in_g  = (const float*)d_in[3];
  const float* in_be = (const float*)d_in[4];
  const float* sp_W  = (const float*)d_in[5];
  const float* sp_b  = (const float*)d_in[6];
  const float* sp_g  = (const float*)d_in[7];
  const float* sp_be = (const float*)d_in[8];
  const float* sp_gate = (const float*)d_in[9];
  const float* sp_w1 = (const float*)d_in[10];
  const float* dn_W  = (const float*)d_in[11];
  const float* dn_b  = (const float*)d_in[12];
  const float* dn_g  = (const float*)d_in[13];
  const float* dn_be = (const float*)d_in[14];
  const float* out_W = (const float*)d_in[15];
  const float* out_b = (const float*)d_in[16];
  float* out = (float*)d_out;

  // ---- workspace layout ----
  char* base = (char*)d_ws;
  size_t off = 0;
  auto alloc = [&](size_t bytes) { void* p = base + off; off = (off + bytes + 255) & ~(size_t)255; return p; };
  float*  xl     = (float*)alloc((size_t)BT * HD * 4);          // 8 MB
  float*  P      = (float*)alloc((size_t)4 * BT * HD * 4);      // 32 MB; eo = P[0:16MB], y = P+4M floats
  float*  eo     = P;                                           // 4096 x 1024 f32 (alias)
  float*  y      = P + (size_t)4 * 1024 * 1024;                 // 2048 x 1024 f32 (alias)
  float*  psum   = (float*)alloc(32 * HD * 4);
  float*  psumsq = (float*)alloc(32 * HD * 4);
  float*  g1o    = (float*)alloc(BT * 4);
  float*  g2o    = (float*)alloc(BT * 4);
  float*  loss   = (float*)alloc(256);
  int*    cnt    = (int*)alloc(256);
  int*    toklist= (int*)alloc(NEXP * MAXR * 4);
  ushort* Hh     = (ushort*)alloc((size_t)BT * HD * 2);
  ushort* Hl     = (ushort*)alloc((size_t)BT * HD * 2);
  ushort* XLh    = (ushort*)alloc((size_t)BT * HD * 2);
  ushort* XLl    = (ushort*)alloc((size_t)BT * HD * 2);
  ushort* inWTh  = (ushort*)alloc((size_t)2048 * HD * 2);
  ushort* inWTl  = (ushort*)alloc((size_t)2048 * HD * 2);
  ushort* spWTh  = (ushort*)alloc((size_t)4 * HD * HD * 2);
  ushort* spWTl  = (ushort*)alloc((size_t)4 * HD * HD * 2);
  ushort* dnWTh  = (ushort*)alloc((size_t)4 * HD * HD * 2);
  ushort* dnWTl  = (ushort*)alloc((size_t)4 * HD * HD * 2);
  ushort* outWTh = (ushort*)alloc((size_t)HD * 256 * 2);
  ushort* outWTl = (ushort*)alloc((size_t)HD * 256 * 2);
  // w1 transpose region; Xh/Xl for input x alias its head (dead after input GEMM,
  // and transpose of w1 is launched after the input GEMM in stream order).
  ushort* w1Th   = (ushort*)alloc((size_t)24 * HD * HD * 2);    // 48 MB
  ushort* w1Tl   = (ushort*)alloc((size_t)24 * HD * HD * 2);    // 48 MB
  ushort* Xh     = w1Th;                                        // 2048x2048 bf16 (8 MB)
  ushort* Xl     = w1Th + (size_t)BT * 2048;                    // next 8 MB

  unsigned lk0[4], lk1[4];
  for (int i = 0; i < 4; ++i) tf2x32(0u, 42u, 0u, (unsigned)i, &lk0[i], &lk1[i]);

  dim3 blk(256);
  init_ws_k<<<1, 64, 0, stream>>>(cnt, loss);

  // ---- weight prep (w1 deferred until after input GEMM) ----
  transpose_split_k<<<dim3(32, 64, 1), blk, 0, stream>>>(in_W, inWTh, inWTl, 2048, HD);
  transpose_split_k<<<dim3(32, 32, 4), blk, 0, stream>>>(sp_W, spWTh, spWTl, HD, HD);
  transpose_split_k<<<dim3(32, 32, 4), blk, 0, stream>>>(dn_W, dnWTh, dnWTl, HD, HD);
  transpose_split_k<<<dim3(8, 32, 1), blk, 0, stream>>>(out_W, outWTh, outWTl, HD, 256);
  split_plain_k<<<(BT * 2048) / 1024, blk, 0, stream>>>(x, Xh, Xl);

  // ---- input layer: split-K=4 GEMM, fused reduce+bias+colsum, BN ----
  gemm_mfma_k<0><<<dim3(8, 16, 4), blk, 0, stream>>>(Xh, Xl, inWTh, inWTl, P,
                                                     nullptr, nullptr, HD, 2048, 16);
  reduce_dense_k<4><<<dim3(4, 32), blk, 0, stream>>>(P, in_b, xl, psum);
  // w1 transpose now (Xh/Xl dead)
  transpose_split_k<<<dim3(32, 32, 24), blk, 0, stream>>>(sp_w1, w1Th, w1Tl, HD, HD);
  var_partial_k<<<dim3(4, 32), blk, 0, stream>>>(xl, psum, psumsq);
  bn_split_k<<<dim3(4, 32), blk, 0, stream>>>(xl, psum, psumsq, in_g, in_be, Hh, Hl);

  // ---- sparse MoE layers ----
  for (int i = 0; i < 4; ++i) {
    gemm_mfma_k<0><<<dim3(8, 16, 4), blk, 0, stream>>>(Hh, Hl, spWTh + (size_t)i * HD * HD,
                                                       spWTl + (size_t)i * HD * HD, P,
                                                       nullptr, nullptr, HD, HD, 8);
    reduce_split_k<4><<<dim3(4, 32), blk, 0, stream>>>(P, sp_b + i * HD, xl, XLh, XLl);
    gating_k<<<BT, 64, 0, stream>>>(xl, sp_gate + (size_t)i * HD * NEXP,
                                    cnt + i * 8, toklist, g1o, g2o, loss, lk0[i], lk1[i]);
    gemm_mfma_k<2><<<dim3(8, 32, NEXP), blk, 0, stream>>>(XLh, XLl,
                                                          w1Th + (size_t)i * NEXP * HD * HD,
                                                          w1Tl + (size_t)i * NEXP * HD * HD,
                                                          eo, cnt + i * 8, toklist, HD, HD, 32);
    combine_sum_k<<<dim3(4, 32), blk, 0, stream>>>(xl, eo, g1o, g2o, y, psum);
    var_partial_k<<<dim3(4, 32), blk, 0, stream>>>(y, psum, psumsq);
    bn_split_k<<<dim3(4, 32), blk, 0, stream>>>(y, psum, psumsq, sp_g + i * HD,
                                                sp_be + i * HD, Hh, Hl);
  }

  // ---- dense layers ----
  for (int i = 0; i < 4; ++i) {
    gemm_mfma_k<0><<<dim3(8, 16, 4), blk, 0, stream>>>(Hh, Hl, dnWTh + (size_t)i * HD * HD,
                                                       dnWTl + (size_t)i * HD * HD, P,
                                                       nullptr, nullptr, HD, HD, 8);
    reduce_dense_k<4><<<dim3(4, 32), blk, 0, stream>>>(P, dn_b + i * HD, xl, psum);
    var_partial_k<<<dim3(4, 32), blk, 0, stream>>>(xl, psum, psumsq);
    bn_split_k<<<dim3(4, 32), blk, 0, stream>>>(xl, psum, psumsq, dn_g + i * HD,
                                                dn_be + i * HD, Hh, Hl);
  }

  // ---- output projection: split-K=8 ----
  gemm_mfma_k<0><<<dim3(2, 16, 8), blk, 0, stream>>>(Hh, Hl, outWTh, outWTl, P,
                                                     nullptr, nullptr, 256, HD, 4);
  reduce_out_k<<<dim3(1, 32), blk, 0, stream>>>(P, out_b, out);
  finalize_loss_k<<<1, 64, 0, stream>>>(loss, out);
}